// Round 13
// baseline (172.417 us; speedup 1.0000x reference)
//
#include <hip/hip_runtime.h>
#include <hip/hip_bf16.h>
#include <math.h>

#define NPOS 3136   // 56*56
#define NB   8
#define LOG2E 1.44269504088896f
#define QSCALE (0.08838834764831845f * LOG2E)   // (1/sqrt(128)) * log2(e)
// softmax computed as p = 2^s directly (offset-invariant; |s| small)

typedef __attribute__((ext_vector_type(8))) short shortx8;    // 8 bf16
typedef __attribute__((ext_vector_type(4))) short shortx4;    // 4 bf16
typedef __attribute__((ext_vector_type(4))) float f32x4;
typedef __attribute__((ext_vector_type(16))) float f32x16;
typedef __attribute__((ext_vector_type(4))) unsigned int uint4v;

struct S8pair { shortx4 lo, hi; };

__device__ __forceinline__ float bf2f(unsigned short u) {
    unsigned int i = ((unsigned int)u) << 16;
    return __builtin_bit_cast(float, i);
}
__device__ __forceinline__ unsigned short f2bf(float f) {
    unsigned int i = __builtin_bit_cast(unsigned int, f);
    i += 0x7FFFu + ((i >> 16) & 1u);   // RNE
    return (unsigned short)(i >> 16);
}
// async global->LDS, 16B per lane; LDS dest = wave-uniform base + lane*16
__device__ __forceinline__ void gll16(const unsigned short* g, unsigned short* l) {
    __builtin_amdgcn_global_load_lds((const __attribute__((address_space(1))) void*)g,
                                     (__attribute__((address_space(3))) void*)l, 16, 0, 0);
}

// ---------------------------------------------------------------------------
// prep 1: weights -> bf16: Wb = [wq*QSCALE | wk | wv | wo], 32768 elements each
// ---------------------------------------------------------------------------
__global__ __launch_bounds__(256) void cast_w(
    const float* __restrict__ wq, const float* __restrict__ wk,
    const float* __restrict__ wv, const float* __restrict__ wo,
    unsigned short* __restrict__ Wb)
{
    const int sel = blockIdx.y;
    const float* src = (sel == 0) ? wq : (sel == 1) ? wk : (sel == 2) ? wv : wo;
    const float sc = (sel == 0) ? QSCALE : 1.0f;
    unsigned short* dst = Wb + sel * 32768;
    int i0 = (blockIdx.x * 256 + threadIdx.x) * 8;
    #pragma unroll
    for (int e = 0; e < 8; ++e) dst[i0 + e] = f2bf(src[i0 + e] * sc);
}

// ---------------------------------------------------------------------------
// prep 2: x (B,256,N) fp32 -> xT (B,N,256) bf16  (LDS transpose, 64x64 tiles)
// ---------------------------------------------------------------------------
__global__ __launch_bounds__(256) void cast_xT(
    const float* __restrict__ x, unsigned short* __restrict__ xT)
{
    const int b = blockIdx.z, c0 = blockIdx.y * 64, n0 = blockIdx.x * 64;
    __shared__ unsigned short Ls[64 * 66];
    const int t = threadIdx.x;
    {
        int r = t >> 2, q4 = t & 3;
        const float* src = x + ((size_t)b * 256 + c0 + r) * NPOS + n0 + q4 * 16;
        #pragma unroll
        for (int i = 0; i < 16; ++i) Ls[r * 66 + q4 * 16 + i] = f2bf(src[i]);
    }
    __syncthreads();
    {
        int j = t >> 2, h4 = t & 3;
        shortx8 v0, v1;
        #pragma unroll
        for (int i = 0; i < 8; ++i) v0[i] = (short)Ls[(h4 * 16 + i) * 66 + j];
        #pragma unroll
        for (int i = 0; i < 8; ++i) v1[i] = (short)Ls[(h4 * 16 + 8 + i) * 66 + j];
        unsigned short* dst = xT + ((size_t)b * NPOS + n0 + j) * 256 + c0 + h4 * 16;
        *reinterpret_cast<shortx8*>(dst) = v0;
        *reinterpret_cast<shortx8*>(dst + 8) = v1;
    }
}

// ---------------------------------------------------------------------------
// K1: QKV projection, bf16 MFMA 16x16x32.  qT,kT (B,N,128); vC (B,128,N)
// ---------------------------------------------------------------------------
__global__ __launch_bounds__(256) void qkv_mfma(
    const unsigned short* __restrict__ xT,
    const unsigned short* __restrict__ Wb,
    const float* __restrict__ bq, const float* __restrict__ bk, const float* __restrict__ bv,
    unsigned short* __restrict__ qT, unsigned short* __restrict__ kT,
    unsigned short* __restrict__ vC)
{
    const int b = blockIdx.z, sel = blockIdx.y, n0 = blockIdx.x * 64;
    const int t = threadIdx.x, lane = t & 63, wave = t >> 6;
    const int l16 = lane & 15, lhi = lane >> 4;
    __shared__ __align__(16) unsigned short Wt[128 * 128];  // 32KB
    __shared__ __align__(16) unsigned short Xt[64 * 128];   // 16KB
    const unsigned short* Wsel = Wb + sel * 32768;
    const float* bias = (sel == 0) ? bq : (sel == 1) ? bk : bv;

    f32x4 acc[2][4];
    #pragma unroll
    for (int ab = 0; ab < 2; ++ab)
        #pragma unroll
        for (int nb = 0; nb < 4; ++nb) acc[ab][nb] = f32x4{0.f, 0.f, 0.f, 0.f};

    for (int ks0 = 0; ks0 < 2; ++ks0) {
        const int k0 = ks0 * 128;
        __syncthreads();
        #pragma unroll
        for (int i = 0; i < 8; ++i) {   // W tile [128][128]
            int c = (wave * 8 + i) * 64 + lane;
            int row = c >> 4, cin = (c & 15) ^ (row & 7);
            gll16(Wsel + (size_t)row * 256 + k0 + cin * 8, &Wt[0] + (wave * 8 + i) * 512);
        }
        #pragma unroll
        for (int i = 0; i < 4; ++i) {   // x tile [64][128]
            int c = (wave * 4 + i) * 64 + lane;
            int row = c >> 4, cin = (c & 15) ^ (row & 7);
            gll16(xT + ((size_t)b * NPOS + n0 + row) * 256 + k0 + cin * 8,
                  &Xt[0] + (wave * 4 + i) * 512);
        }
        __syncthreads();
        #pragma unroll
        for (int ks = 0; ks < 4; ++ks) {
            shortx8 aW[2];
            #pragma unroll
            for (int ab = 0; ab < 2; ++ab) {
                int row = wave * 32 + ab * 16 + l16;
                int idx = (row * 128 + ks * 32 + lhi * 8) ^ ((row & 7) << 3);
                aW[ab] = *reinterpret_cast<const shortx8*>(Wt + idx);
            }
            #pragma unroll
            for (int nb = 0; nb < 4; ++nb) {
                int row = nb * 16 + l16;
                int idx = (row * 128 + ks * 32 + lhi * 8) ^ ((row & 7) << 3);
                shortx8 bX = *reinterpret_cast<const shortx8*>(Xt + idx);
                acc[0][nb] = __builtin_amdgcn_mfma_f32_16x16x32_bf16(aW[0], bX, acc[0][nb], 0, 0, 0);
                acc[1][nb] = __builtin_amdgcn_mfma_f32_16x16x32_bf16(aW[1], bX, acc[1][nb], 0, 0, 0);
            }
        }
    }
    const int strip = wave * 32;
    if (sel < 2) {
        unsigned short* dst0 = ((sel == 0) ? qT : kT) + (size_t)b * NPOS * 128;
        const float bsc = (sel == 0) ? QSCALE : 1.0f;
        #pragma unroll
        for (int ab = 0; ab < 2; ++ab) {
            int ocb = strip + ab * 16 + lhi * 4;
            float bb[4];
            #pragma unroll
            for (int j = 0; j < 4; ++j) bb[j] = bias[ocb + j] * bsc;
            #pragma unroll
            for (int nb = 0; nb < 4; ++nb) {
                int n = n0 + nb * 16 + l16;
                shortx4 u;
                #pragma unroll
                for (int j = 0; j < 4; ++j) u[j] = (short)f2bf(acc[ab][nb][j] + bb[j]);
                *reinterpret_cast<shortx4*>(dst0 + (size_t)n * 128 + ocb) = u;
            }
        }
    } else {
        #pragma unroll
        for (int ab = 0; ab < 2; ++ab)
            #pragma unroll
            for (int j = 0; j < 4; ++j) {
                int oc = strip + ab * 16 + lhi * 4 + j;
                float bb = bias[oc];
                unsigned short* dst = vC + ((size_t)b * 128 + oc) * NPOS + n0;
                #pragma unroll
                for (int nb = 0; nb < 4; ++nb)
                    dst[nb * 16 + l16] = f2bf(acc[ab][nb][j] + bb);
            }
    }
}

// ---------------------------------------------------------------------------
// K2: flash attention, 32x32x16 MFMA, in-register P.
// PAIR-TILE (r12, halves LDS reads per MFMA: K/V frags read once, used for
// both q-tiles) x Z-SPLIT x2 (r10: partial o/lr per key-half, merged in
// out_proj) x r9 sync (2-deep counted-vmcnt pipeline, raw barriers).
// Grid 400 = 2z x 8b x 25 pairs; 200 == 0 mod 8 so id&7 = XCD-affine batch.
// LDS 64KB (K dbuf + V dbuf) -> 2 blocks/CU resident.
// ---------------------------------------------------------------------------
__global__ __launch_bounds__(256, 2) void attn_kernel(
    const unsigned short* __restrict__ qT,
    const unsigned short* __restrict__ kT,
    const unsigned short* __restrict__ vC,
    unsigned short* __restrict__ ao,     // [2][B*N*128]
    float* __restrict__ lrG)             // [2][B*N]
{
    const int id = blockIdx.x;
    const int z = id / 200;
    const int b = id & 7;                 // XCD-affine batch (200 % 8 == 0)
    const int ti = (id % 200) >> 3;       // 0..24
    const int lone = (ti == 24);
    const int n0 = ti * 128;
    const int kt0 = z ? 25 : 0, kt1 = z ? 49 : 25;
    const int t = threadIdx.x, lane = t & 63, wave = t >> 6;
    const int l31 = lane & 31, h = lane >> 5;
    const int qsub = wave >> 1, kh = wave & 1;

    __shared__ __align__(16) unsigned short KsB[2][64 * 128];   // 32KB
    __shared__ __align__(16) unsigned short VsB[2][128 * 64];   // 32KB

    // Q fragments: 2 q-tiles x 32 q-rows per wave
    shortx8 aQ[2][8];
    #pragma unroll
    for (int qt = 0; qt < 2; ++qt) {
        int qb = n0 + (lone ? 0 : qt * 64) + qsub * 32 + l31;
        const unsigned short* qp = qT + ((size_t)b * NPOS + qb) * 128 + h * 8;
        #pragma unroll
        for (int kk = 0; kk < 8; ++kk)
            aQ[qt][kk] = *reinterpret_cast<const shortx8*>(qp + kk * 16);
    }

    // staging sources (pre-swizzled so linear LDS dest == swizzled tile)
    const unsigned short* kSrc[4];
    const unsigned short* vSrc[4];
    unsigned sDst[4];
    #pragma unroll
    for (int i = 0; i < 4; ++i) {
        int c = (wave * 4 + i) * 64 + lane;
        int rK = c >> 4, cK = (c & 15) ^ (rK & 15);      // K tile [64][128]
        kSrc[i] = kT + ((size_t)b * NPOS + rK) * 128 + cK * 8;
        int rV = c >> 3, cV = (c & 7) ^ (rV & 7);        // V tile [128][64]
        vSrc[i] = vC + ((size_t)b * 128 + rV) * NPOS + cV * 8;
        sDst[i] = (wave * 4 + i) * 512;
    }

    // loop-invariant LDS read offsets
    unsigned kIdx[8];
    {
        int rowK = kh * 32 + l31;
        #pragma unroll
        for (int kk = 0; kk < 8; ++kk)
            kIdx[kk] = rowK * 128 + (((kk * 2 + h) ^ (rowK & 15)) * 8);
    }
    unsigned vIdx[4][2][2];
    #pragma unroll
    for (int ob = 0; ob < 4; ++ob) {
        int rowV = ob * 32 + l31;
        #pragma unroll
        for (int ks = 0; ks < 2; ++ks)
            #pragma unroll
            for (int rr = 0; rr < 2; ++rr)
                vIdx[ob][ks][rr] = rowV * 64 + h * 4
                    + (((kh * 4 + ks * 2 + rr) * 8) ^ ((rowV & 7) * 8));
    }

    f32x16 o[2][4];
    #pragma unroll
    for (int qt = 0; qt < 2; ++qt)
        #pragma unroll
        for (int ob = 0; ob < 4; ++ob)
            #pragma unroll
            for (int r2 = 0; r2 < 16; ++r2) o[qt][ob][r2] = 0.f;
    float lrP[2] = {0.f, 0.f};

    f32x16 FZ;
    #pragma unroll
    for (int r2 = 0; r2 < 16; ++r2) FZ[r2] = 0.f;
    asm volatile("" : "+v"(FZ));

    #define STAGE(kt_, buf_)                                                          \
        _Pragma("unroll")                                                             \
        for (int i = 0; i < 4; ++i) {                                                 \
            gll16(kSrc[i] + (size_t)(kt_) * 8192, &KsB[buf_][0] + sDst[i]);           \
            gll16(vSrc[i] + (kt_) * 64, &VsB[buf_][0] + sDst[i]);                     \
        }

    // QK both q-tiles (K-frag read once), exp, PV both q-tiles (V-frag once)
    #define COMPUTE(Ks, Vs)                                                           \
    {                                                                                 \
        f32x16 s0_, s1_;                                                              \
        __builtin_amdgcn_s_setprio(1);                                                \
        {                                                                             \
            shortx8 kf0 = *reinterpret_cast<const shortx8*>((Ks) + kIdx[0]);          \
            s0_ = __builtin_amdgcn_mfma_f32_32x32x16_bf16(kf0, aQ[0][0], FZ, 0, 0, 0);\
            s1_ = __builtin_amdgcn_mfma_f32_32x32x16_bf16(kf0, aQ[1][0], FZ, 0, 0, 0);\
        }                                                                             \
        _Pragma("unroll")                                                             \
        for (int kk = 1; kk < 8; ++kk) {                                              \
            shortx8 kf = *reinterpret_cast<const shortx8*>((Ks) + kIdx[kk]);          \
            s0_ = __builtin_amdgcn_mfma_f32_32x32x16_bf16(kf, aQ[0][kk], s0_, 0, 0, 0); \
            s1_ = __builtin_amdgcn_mfma_f32_32x32x16_bf16(kf, aQ[1][kk], s1_, 0, 0, 0); \
        }                                                                             \
        __builtin_amdgcn_s_setprio(0);                                                \
        unsigned pk[2][8];                                                            \
        _Pragma("unroll")                                                             \
        for (int g = 0; g < 4; ++g) {                                                 \
            float a0 = exp2f(s0_[g * 4 + 0]), a1 = exp2f(s0_[g * 4 + 1]);             \
            float a2 = exp2f(s0_[g * 4 + 2]), a3 = exp2f(s0_[g * 4 + 3]);             \
            float c0 = exp2f(s1_[g * 4 + 0]), c1 = exp2f(s1_[g * 4 + 1]);             \
            float c2 = exp2f(s1_[g * 4 + 2]), c3 = exp2f(s1_[g * 4 + 3]);             \
            lrP[0] += (a0 + a1) + (a2 + a3);                                          \
            lrP[1] += (c0 + c1) + (c2 + c3);                                          \
            asm("v_cvt_pk_bf16_f32 %0, %1, %2" : "=v"(pk[0][g * 2 + 0]) : "v"(a0), "v"(a1)); \
            asm("v_cvt_pk_bf16_f32 %0, %1, %2" : "=v"(pk[0][g * 2 + 1]) : "v"(a2), "v"(a3)); \
            asm("v_cvt_pk_bf16_f32 %0, %1, %2" : "=v"(pk[1][g * 2 + 0]) : "v"(c0), "v"(c1)); \
            asm("v_cvt_pk_bf16_f32 %0, %1, %2" : "=v"(pk[1][g * 2 + 1]) : "v"(c2), "v"(c3)); \
        }                                                                             \
        __builtin_amdgcn_s_setprio(1);                                                \
        _Pragma("unroll")                                                             \
        for (int ks = 0; ks < 2; ++ks) {                                              \
            uint4v pv0 = {pk[0][ks * 4 + 0], pk[0][ks * 4 + 1], pk[0][ks * 4 + 2], pk[0][ks * 4 + 3]}; \
            uint4v pv1 = {pk[1][ks * 4 + 0], pk[1][ks * 4 + 1], pk[1][ks * 4 + 2], pk[1][ks * 4 + 3]}; \
            shortx8 PA0 = __builtin_bit_cast(shortx8, pv0);                           \
            shortx8 PA1 = __builtin_bit_cast(shortx8, pv1);                           \
            _Pragma("unroll")                                                         \
            for (int ob = 0; ob < 4; ++ob) {                                          \
                shortx4 lo = *reinterpret_cast<const shortx4*>((Vs) + vIdx[ob][ks][0]); \
                shortx4 hi = *reinterpret_cast<const shortx4*>((Vs) + vIdx[ob][ks][1]); \
                shortx8 bV = __builtin_bit_cast(shortx8, S8pair{lo, hi});             \
                o[0][ob] = __builtin_amdgcn_mfma_f32_32x32x16_bf16(PA0, bV, o[0][ob], 0, 0, 0); \
                o[1][ob] = __builtin_amdgcn_mfma_f32_32x32x16_bf16(PA1, bV, o[1][ob], 0, 0, 0); \
            }                                                                         \
        }                                                                             \
        __builtin_amdgcn_s_setprio(0);                                                \
    }

    #define SB __builtin_amdgcn_sched_barrier(0)

    // prologue: 2-deep prefetch (16 loads outstanding)
    STAGE(kt0, 0)
    STAGE(kt0 + 1, 1)

    int cur = 0;
    for (int kt = kt0; kt < kt1 - 1; ++kt) {
        asm volatile("s_waitcnt vmcnt(8)" ::: "memory");
        SB; __builtin_amdgcn_s_barrier(); SB;
        COMPUTE(&KsB[cur][0], &VsB[cur][0])
        SB; __builtin_amdgcn_s_barrier(); SB;
        if (kt < kt1 - 2) { STAGE(kt + 2, cur) }
        cur ^= 1;
    }
    {   // peeled last tile
        asm volatile("s_waitcnt vmcnt(0)" ::: "memory");
        SB; __builtin_amdgcn_s_barrier(); SB;
        COMPUTE(&KsB[cur][0], &VsB[cur][0])
    }
    __syncthreads();   // done with all LDS; reuse as merge scratch

    // ---- epilogue: per q-tile, merge kh halves, store partial o + lr ----
    float* Om = reinterpret_cast<float*>(&KsB[0][0]);        // 32KB f32 [64][128]
    float* lrS = reinterpret_cast<float*>(&VsB[1][0]);       // 256B
    unsigned short* Oo = &VsB[0][0];                         // 16KB bf16 [64][128]

    for (int qt = 0; qt < (lone ? 1 : 2); ++qt) {
        float lr2 = lrP[qt] + __shfl_xor(lrP[qt], 32);
        if (kh == 1) {
            #pragma unroll
            for (int ob = 0; ob < 4; ++ob)
                #pragma unroll
                for (int r2 = 0; r2 < 16; ++r2) {
                    int q = qsub * 32 + (r2 & 3) + 8 * (r2 >> 2) + 4 * h;
                    Om[q * 128 + ob * 32 + l31] = o[qt][ob][r2];
                }
            if (lane < 32) lrS[qsub * 32 + l31] = lr2;
        }
        __syncthreads();
        if (kh == 0) {
            #pragma unroll
            for (int ob = 0; ob < 4; ++ob)
                #pragma unroll
                for (int r2 = 0; r2 < 16; ++r2) {
                    int q = qsub * 32 + (r2 & 3) + 8 * (r2 >> 2) + 4 * h;
                    int idx = q * 128 + ob * 32 + l31;
                    Oo[idx] = f2bf(o[qt][ob][r2] + Om[idx]);
                }
            if (lane < 32)
                lrG[((size_t)z * NB + b) * NPOS + n0 + qt * 64 + qsub * 32 + l31]
                    = lr2 + lrS[qsub * 32 + l31];
        }
        __syncthreads();
        {
            const shortx8* src = reinterpret_cast<const shortx8*>(Oo);
            shortx8* dst = reinterpret_cast<shortx8*>(
                ao + (((size_t)z * NB + b) * NPOS + n0 + qt * 64) * 128);
            #pragma unroll
            for (int i = 0; i < 4; ++i) dst[t + 256 * i] = src[t + 256 * i];
        }
        __syncthreads();
    }
    #undef STAGE
    #undef COMPUTE
    #undef SB
}

// ---------------------------------------------------------------------------
// K3: output projection + z-merge + normalization + bias + residual.
// y = x + bo + (wo . (ao0 + ao1)) / (lr0 + lr1)   (dual f32 MFMA accumulate)
// ---------------------------------------------------------------------------
__global__ __launch_bounds__(256) void out_proj(
    const float* __restrict__ x,
    const unsigned short* __restrict__ Wb,
    const float* __restrict__ bo,
    const unsigned short* __restrict__ ao,   // [2][B*N*128]
    const float* __restrict__ lrG,           // [2][B*N]
    float* __restrict__ y)
{
    const int b = blockIdx.y, n0 = blockIdx.x * 64;
    const int t = threadIdx.x, lane = t & 63, wave = t >> 6;
    const int l16 = lane & 15, lhi = lane >> 4;
    __shared__ __align__(16) unsigned short Wt[256 * 128];     // 64KB
    __shared__ __align__(16) unsigned short At[2][64 * 128];   // 32KB
    const unsigned short* wo = Wb + 98304;

    #pragma unroll
    for (int i = 0; i < 16; ++i) {   // wo tile [256][128]
        int c = (wave * 16 + i) * 64 + lane;
        int row = c >> 4, cin = (c & 15) ^ (row & 7);
        gll16(wo + (size_t)row * 128 + cin * 8, &Wt[0] + (wave * 16 + i) * 512);
    }
    #pragma unroll
    for (int zz = 0; zz < 2; ++zz)
        #pragma unroll
        for (int i = 0; i < 4; ++i) {    // ao tiles [64][128] x2
            int c = (wave * 4 + i) * 64 + lane;
            int row = c >> 4, cin = (c & 15) ^ (row & 7);
            gll16(ao + (((size_t)zz * NB + b) * NPOS + n0 + row) * 128 + cin * 8,
                  &At[zz][0] + (wave * 4 + i) * 512);
        }
    __syncthreads();

    f32x4 acc[4][4];
    #pragma unroll
    for (int ab = 0; ab < 4; ++ab)
        #pragma unroll
        for (int nb = 0; nb < 4; ++nb) acc[ab][nb] = f32x4{0.f, 0.f, 0.f, 0.f};

    const int strip = wave * 64;
    #pragma unroll
    for (int ks = 0; ks < 4; ++ks) {
        shortx8 aW[4];
        #pragma unroll
        for (int ab = 0; ab < 4; ++ab) {
            int row = strip + ab * 16 + l16;
            int idx = (row * 128 + ks * 32 + lhi * 8) ^ ((row & 7) << 3);
            aW[ab] = *reinterpret_cast<const shortx8*>(Wt + idx);
        }
        #pragma unroll
        for (int nb = 0; nb < 4; ++nb) {
            int row = nb * 16 + l16;
            int idx = (row * 128 + ks * 32 + lhi * 8) ^ ((row & 7) << 3);
            shortx8 bA0 = *reinterpret_cast<const shortx8*>(&At[0][0] + idx);
            shortx8 bA1 = *reinterpret_cast<const shortx8*>(&At[1][0] + idx);
            #pragma unroll
            for (int ab = 0; ab < 4; ++ab) {
                acc[ab][nb] = __builtin_amdgcn_mfma_f32_16x16x32_bf16(aW[ab], bA0, acc[ab][nb], 0, 0, 0);
                acc[ab][nb] = __builtin_amdgcn_mfma_f32_16x16x32_bf16(aW[ab], bA1, acc[ab][nb], 0, 0, 0);
            }
        }
    }

    float inv[4];
    #pragma unroll
    for (int nb = 0; nb < 4; ++nb) {
        size_t n = (size_t)b * NPOS + n0 + nb * 16 + l16;
        inv[nb] = 1.0f / (lrG[n] + lrG[(size_t)NB * NPOS + n]);
    }

    #pragma unroll
    for (int ab = 0; ab < 4; ++ab)
        #pragma unroll
        for (int j = 0; j < 4; ++j) {
            int oc = strip + ab * 16 + lhi * 4 + j;
            float bb = bo[oc];
            const float* xr = x + ((size_t)b * 256 + oc) * NPOS + n0;
            float* yr = y + ((size_t)b * 256 + oc) * NPOS + n0;
            #pragma unroll
            for (int nb = 0; nb < 4; ++nb) {
                int n = nb * 16 + l16;
                yr[n] = xr[n] + bb + acc[ab][nb][j] * inv[nb];
            }
        }
}

extern "C" void kernel_launch(void* const* d_in, const int* in_sizes, int n_in,
                              void* d_out, int out_size, void* d_ws, size_t ws_size,
                              hipStream_t stream)
{
    const float* x  = (const float*)d_in[0];
    const float* wq = (const float*)d_in[1];
    const float* bq = (const float*)d_in[2];
    const float* wk = (const float*)d_in[3];
    const float* bk = (const float*)d_in[4];
    const float* wv = (const float*)d_in[5];
    const float* bv = (const float*)d_in[6];
    const float* wo = (const float*)d_in[7];
    const float* bo = (const float*)d_in[8];
    float* y = (float*)d_out;

    const size_t sz = (size_t)NB * NPOS * 128;     // 3,211,264 elements
    unsigned short* qT = (unsigned short*)d_ws;    // sz
    unsigned short* kT = qT + sz;                  // sz
    unsigned short* vC = kT + sz;                  // sz
    unsigned short* xT = vC + sz;                  // 2*sz  (B,N,256)
    unsigned short* ao = xT;                       // [2][sz] aliases xT (dead after qkv)
    unsigned short* Wb = xT + 2 * sz;              // 131072
    float* lrG = (float*)(Wb + 131072);            // [2][B*N] f32 (200KB)
    // total ws use ~32.6 MB

    cast_w  <<<dim3(16, 4),       256, 0, stream>>>(wq, wk, wv, wo, Wb);
    cast_xT <<<dim3(49, 4, NB),   256, 0, stream>>>(x, xT);
    qkv_mfma<<<dim3(49, 3, NB),   256, 0, stream>>>(xT, Wb, bq, bk, bv, qT, kT, vC);
    attn_kernel<<<dim3(400),      256, 0, stream>>>(qT, kT, vC, ao, lrG);
    out_proj<<<dim3(49, NB),      256, 0, stream>>>(x, Wb, bo, ao, lrG, y);
}

// Round 14
// 170.764 us; speedup vs baseline: 1.0097x; 1.0097x over previous
//
#include <hip/hip_runtime.h>
#include <hip/hip_bf16.h>
#include <math.h>

#define NPOS 3136   // 56*56
#define NB   8
#define LOG2E 1.44269504088896f
#define QSCALE (0.08838834764831845f * LOG2E)   // (1/sqrt(128)) * log2(e)
// softmax computed as p = 2^s directly (offset-invariant; |s| small)

typedef __attribute__((ext_vector_type(8))) short shortx8;    // 8 bf16
typedef __attribute__((ext_vector_type(4))) short shortx4;    // 4 bf16
typedef __attribute__((ext_vector_type(4))) float f32x4;
typedef __attribute__((ext_vector_type(16))) float f32x16;
typedef __attribute__((ext_vector_type(4))) unsigned int uint4v;

struct S8pair { shortx4 lo, hi; };

__device__ __forceinline__ float bf2f(unsigned short u) {
    unsigned int i = ((unsigned int)u) << 16;
    return __builtin_bit_cast(float, i);
}
__device__ __forceinline__ unsigned short f2bf(float f) {
    unsigned int i = __builtin_bit_cast(unsigned int, f);
    i += 0x7FFFu + ((i >> 16) & 1u);   // RNE
    return (unsigned short)(i >> 16);
}
// async global->LDS, 16B per lane; LDS dest = wave-uniform base + lane*16
__device__ __forceinline__ void gll16(const unsigned short* g, unsigned short* l) {
    __builtin_amdgcn_global_load_lds((const __attribute__((address_space(1))) void*)g,
                                     (__attribute__((address_space(3))) void*)l, 16, 0, 0);
}

// ---------------------------------------------------------------------------
// prep: weights -> bf16: Wb = [wq*QSCALE | wk | wv | wo], 32768 elements each
// ---------------------------------------------------------------------------
__global__ __launch_bounds__(256) void cast_w(
    const float* __restrict__ wq, const float* __restrict__ wk,
    const float* __restrict__ wv, const float* __restrict__ wo,
    unsigned short* __restrict__ Wb)
{
    const int sel = blockIdx.y;
    const float* src = (sel == 0) ? wq : (sel == 1) ? wk : (sel == 2) ? wv : wo;
    const float sc = (sel == 0) ? QSCALE : 1.0f;
    unsigned short* dst = Wb + sel * 32768;
    int i0 = (blockIdx.x * 256 + threadIdx.x) * 8;
    #pragma unroll
    for (int e = 0; e < 8; ++e) dst[i0 + e] = f2bf(src[i0 + e] * sc);
}

// ---------------------------------------------------------------------------
// K1: FUSED cast + QKV projection.  Reads x (B,256,N) fp32 directly; builds
// Xt[64][256] bf16 (transposed, XOR-swizzled) in LDS via the cast_xT
// transpose pattern; then 3 sels x 2 k-halves of bf16 MFMA over the same Xt.
// Outputs qT,kT (B,N,128) (q pre-scaled, bias included); vC (B,128,N).
// Replaces the former cast_xT kernel + 3x xT re-read.
// ---------------------------------------------------------------------------
__global__ __launch_bounds__(256) void qkv_fused(
    const float* __restrict__ x,
    const unsigned short* __restrict__ Wb,
    const float* __restrict__ bq, const float* __restrict__ bk, const float* __restrict__ bv,
    unsigned short* __restrict__ qT, unsigned short* __restrict__ kT,
    unsigned short* __restrict__ vC)
{
    const int b = blockIdx.y, n0 = blockIdx.x * 64;
    const int t = threadIdx.x, lane = t & 63, wave = t >> 6;
    const int l16 = lane & 15, lhi = lane >> 4;
    __shared__ __align__(16) unsigned short Xt[64 * 256];   // 32KB
    __shared__ __align__(16) unsigned short Wt[128 * 128];  // 32KB
    __shared__ unsigned short Ls[64 * 66];                  // 8.25KB

    // ---- build Xt: x[c][n] fp32 -> Xt[n][c] bf16 (4 chunks of 64 c) ----
    for (int cc = 0; cc < 4; ++cc) {
        {
            int r = t >> 2, q4 = t & 3;
            const float* src = x + ((size_t)b * 256 + cc * 64 + r) * NPOS + n0 + q4 * 16;
            #pragma unroll
            for (int i = 0; i < 16; ++i) Ls[r * 66 + q4 * 16 + i] = f2bf(src[i]);
        }
        __syncthreads();
        {
            int j = t >> 2, h4 = t & 3;
            shortx8 v0, v1;
            #pragma unroll
            for (int i = 0; i < 8; ++i) v0[i] = (short)Ls[(h4 * 16 + i) * 66 + j];
            #pragma unroll
            for (int i = 0; i < 8; ++i) v1[i] = (short)Ls[(h4 * 16 + 8 + i) * 66 + j];
            int X = (j & 7) << 3;
            int c0 = cc * 64 + h4 * 16;
            *reinterpret_cast<shortx8*>(&Xt[j * 256 + (c0 ^ X)]) = v0;
            *reinterpret_cast<shortx8*>(&Xt[j * 256 + ((c0 + 8) ^ X)]) = v1;
        }
        __syncthreads();
    }

    // ---- 3 sels x 2 k-halves over the block-resident Xt ----
    for (int sel = 0; sel < 3; ++sel) {
        const unsigned short* Wsel = Wb + sel * 32768;
        const float* bias = (sel == 0) ? bq : (sel == 1) ? bk : bv;

        f32x4 acc[2][4];
        #pragma unroll
        for (int ab = 0; ab < 2; ++ab)
            #pragma unroll
            for (int nb = 0; nb < 4; ++nb) acc[ab][nb] = f32x4{0.f, 0.f, 0.f, 0.f};

        for (int ks0 = 0; ks0 < 2; ++ks0) {
            const int k0 = ks0 * 128;
            __syncthreads();   // prior MFMA reads of Wt complete
            #pragma unroll
            for (int i = 0; i < 8; ++i) {   // W tile [128][128]
                int c = (wave * 8 + i) * 64 + lane;
                int row = c >> 4, cin = (c & 15) ^ (row & 7);
                gll16(Wsel + (size_t)row * 256 + k0 + cin * 8, &Wt[0] + (wave * 8 + i) * 512);
            }
            __syncthreads();   // drains gll16 (vmcnt 0) + sync
            #pragma unroll
            for (int ks = 0; ks < 4; ++ks) {
                shortx8 aW[2];
                #pragma unroll
                for (int ab = 0; ab < 2; ++ab) {
                    int row = wave * 32 + ab * 16 + l16;
                    int idx = (row * 128 + ks * 32 + lhi * 8) ^ ((row & 7) << 3);
                    aW[ab] = *reinterpret_cast<const shortx8*>(Wt + idx);
                }
                #pragma unroll
                for (int nb = 0; nb < 4; ++nb) {
                    int row = nb * 16 + l16;
                    int idx = row * 256 + ((k0 + ks * 32 + lhi * 8) ^ ((row & 7) << 3));
                    shortx8 bX = *reinterpret_cast<const shortx8*>(Xt + idx);
                    acc[0][nb] = __builtin_amdgcn_mfma_f32_16x16x32_bf16(aW[0], bX, acc[0][nb], 0, 0, 0);
                    acc[1][nb] = __builtin_amdgcn_mfma_f32_16x16x32_bf16(aW[1], bX, acc[1][nb], 0, 0, 0);
                }
            }
        }

        const int strip = wave * 32;
        if (sel < 2) {
            unsigned short* dst0 = ((sel == 0) ? qT : kT) + (size_t)b * NPOS * 128;
            const float bsc = (sel == 0) ? QSCALE : 1.0f;
            #pragma unroll
            for (int ab = 0; ab < 2; ++ab) {
                int ocb = strip + ab * 16 + lhi * 4;
                float bb[4];
                #pragma unroll
                for (int j = 0; j < 4; ++j) bb[j] = bias[ocb + j] * bsc;
                #pragma unroll
                for (int nb = 0; nb < 4; ++nb) {
                    int n = n0 + nb * 16 + l16;
                    shortx4 u;
                    #pragma unroll
                    for (int j = 0; j < 4; ++j) u[j] = (short)f2bf(acc[ab][nb][j] + bb[j]);
                    *reinterpret_cast<shortx4*>(dst0 + (size_t)n * 128 + ocb) = u;
                }
            }
        } else {
            #pragma unroll
            for (int ab = 0; ab < 2; ++ab)
                #pragma unroll
                for (int j = 0; j < 4; ++j) {
                    int oc = strip + ab * 16 + lhi * 4 + j;
                    float bb = bias[oc];
                    unsigned short* dst = vC + ((size_t)b * 128 + oc) * NPOS + n0;
                    #pragma unroll
                    for (int nb = 0; nb < 4; ++nb)
                        dst[nb * 16 + l16] = f2bf(acc[ab][nb][j] + bb);
                }
        }
    }
}

// ---------------------------------------------------------------------------
// K2: flash attention, 32x32x16 MFMA, in-register P.  r11 structure with
// TRIPLE-buffered K/V and ONE barrier per tile: STAGE(kt+2) overwrites
// buf[(kt-1)%3], whose readers all finished before barrier(kt) -> the
// end-of-compute barrier is redundant and removed.  Counted vmcnt(8),
// batch-per-XCD swizzle, single-chain QK with persistent-zero C, p = 2^s.
// LDS 72.5KB -> 2 blocks/CU.
// ---------------------------------------------------------------------------
__global__ __launch_bounds__(256) void attn_kernel(
    const unsigned short* __restrict__ qT,
    const unsigned short* __restrict__ kT,
    const unsigned short* __restrict__ vC,
    unsigned short* __restrict__ ao,
    float* __restrict__ lrG)
{
    const int i_lin = blockIdx.y * 49 + blockIdx.x;
    const int b = i_lin & 7;                 // XCD-affine batch
    const int n0 = (i_lin >> 3) * 64;        // query tile
    const int t = threadIdx.x, lane = t & 63, wave = t >> 6;
    const int l31 = lane & 31, h = lane >> 5;
    const int qsub = wave >> 1, kh = wave & 1;
    const int NT = NPOS / 64;                // 49

    __shared__ __align__(16) unsigned short KsB[3][64 * 128];   // 48KB
    __shared__ __align__(16) unsigned short VsB[3][128 * 64];   // 24KB
    __shared__ float lrS[64];

    // Q fragments (B operand): 32 q-rows, 8 k-chunks of 16 ch
    shortx8 aQ[8];
    {
        const unsigned short* qp = qT + ((size_t)b * NPOS + n0 + qsub * 32 + l31) * 128 + h * 8;
        #pragma unroll
        for (int kk = 0; kk < 8; ++kk)
            aQ[kk] = *reinterpret_cast<const shortx8*>(qp + kk * 16);
    }

    // staging sources (pre-swizzled so linear LDS dest == swizzled tile)
    const unsigned short* kSrc[4];
    const unsigned short* vSrc[4];
    unsigned sDst[4];
    #pragma unroll
    for (int i = 0; i < 4; ++i) {
        int c = (wave * 4 + i) * 64 + lane;
        int rK = c >> 4, cK = (c & 15) ^ (rK & 15);      // K tile [64][128]
        kSrc[i] = kT + ((size_t)b * NPOS + rK) * 128 + cK * 8;
        int rV = c >> 3, cV = (c & 7) ^ (rV & 7);        // V tile [128][64]
        vSrc[i] = vC + ((size_t)b * 128 + rV) * NPOS + cV * 8;
        sDst[i] = (wave * 4 + i) * 512;
    }

    // loop-invariant LDS read offsets
    unsigned kIdx[8];
    {
        int rowK = kh * 32 + l31;
        #pragma unroll
        for (int kk = 0; kk < 8; ++kk)
            kIdx[kk] = rowK * 128 + (((kk * 2 + h) ^ (rowK & 15)) * 8);
    }
    unsigned vIdx[4][2][2];
    #pragma unroll
    for (int ob = 0; ob < 4; ++ob) {
        int rowV = ob * 32 + l31;
        #pragma unroll
        for (int ks = 0; ks < 2; ++ks)
            #pragma unroll
            for (int rr = 0; rr < 2; ++rr)
                vIdx[ob][ks][rr] = rowV * 64 + h * 4
                    + (((kh * 4 + ks * 2 + rr) * 8) ^ ((rowV & 7) * 8));
    }

    f32x16 o[4];
    #pragma unroll
    for (int ob = 0; ob < 4; ++ob)
        #pragma unroll
        for (int r2 = 0; r2 < 16; ++r2) o[ob][r2] = 0.f;
    float lrP = 0.f;

    f32x16 FZ;
    #pragma unroll
    for (int r2 = 0; r2 < 16; ++r2) FZ[r2] = 0.f;
    asm volatile("" : "+v"(FZ));

    #define STAGE(kt_, buf_)                                                          \
        _Pragma("unroll")                                                             \
        for (int i = 0; i < 4; ++i) {                                                 \
            gll16(kSrc[i] + (size_t)(kt_) * 8192, &KsB[buf_][0] + sDst[i]);           \
            gll16(vSrc[i] + (kt_) * 64, &VsB[buf_][0] + sDst[i]);                     \
        }

    #define COMPUTE(Ks, Vs)                                                           \
    {                                                                                 \
        f32x16 s_;                                                                    \
        __builtin_amdgcn_s_setprio(1);                                                \
        {                                                                             \
            shortx8 k0 = *reinterpret_cast<const shortx8*>((Ks) + kIdx[0]);           \
            s_ = __builtin_amdgcn_mfma_f32_32x32x16_bf16(k0, aQ[0], FZ, 0, 0, 0);     \
        }                                                                             \
        _Pragma("unroll")                                                             \
        for (int kk = 1; kk < 8; ++kk) {                                              \
            shortx8 kf = *reinterpret_cast<const shortx8*>((Ks) + kIdx[kk]);          \
            s_ = __builtin_amdgcn_mfma_f32_32x32x16_bf16(kf, aQ[kk], s_, 0, 0, 0);    \
        }                                                                             \
        __builtin_amdgcn_s_setprio(0);                                                \
        unsigned pk[8];                                                               \
        _Pragma("unroll")                                                             \
        for (int g = 0; g < 4; ++g) {                                                 \
            float p0 = exp2f(s_[g * 4 + 0]);                                          \
            float p1 = exp2f(s_[g * 4 + 1]);                                          \
            float p2 = exp2f(s_[g * 4 + 2]);                                          \
            float p3 = exp2f(s_[g * 4 + 3]);                                          \
            lrP += (p0 + p1) + (p2 + p3);                                             \
            asm("v_cvt_pk_bf16_f32 %0, %1, %2" : "=v"(pk[g * 2 + 0]) : "v"(p0), "v"(p1)); \
            asm("v_cvt_pk_bf16_f32 %0, %1, %2" : "=v"(pk[g * 2 + 1]) : "v"(p2), "v"(p3)); \
        }                                                                             \
        __builtin_amdgcn_s_setprio(1);                                                \
        _Pragma("unroll")                                                             \
        for (int ks = 0; ks < 2; ++ks) {                                              \
            uint4v pv = {pk[ks * 4 + 0], pk[ks * 4 + 1], pk[ks * 4 + 2], pk[ks * 4 + 3]}; \
            shortx8 PA = __builtin_bit_cast(shortx8, pv);                             \
            _Pragma("unroll")                                                         \
            for (int ob = 0; ob < 4; ++ob) {                                          \
                shortx4 lo = *reinterpret_cast<const shortx4*>((Vs) + vIdx[ob][ks][0]); \
                shortx4 hi = *reinterpret_cast<const shortx4*>((Vs) + vIdx[ob][ks][1]); \
                shortx8 bV = __builtin_bit_cast(shortx8, S8pair{lo, hi});             \
                o[ob] = __builtin_amdgcn_mfma_f32_32x32x16_bf16(PA, bV, o[ob], 0, 0, 0); \
            }                                                                         \
        }                                                                             \
        __builtin_amdgcn_s_setprio(0);                                                \
    }

    #define SB __builtin_amdgcn_sched_barrier(0)

    // prologue: 2-deep prefetch (16 loads outstanding)
    STAGE(0, 0)
    STAGE(1, 1)

    int rd = 0, wr = 2;
    for (int kt = 0; kt < NT - 1; ++kt) {
        asm volatile("s_waitcnt vmcnt(8)" ::: "memory");
        SB; __builtin_amdgcn_s_barrier(); SB;   // all waves' tile-kt loads retired
        if (kt < NT - 2) { STAGE(kt + 2, wr) }  // overwrites buf[(kt-1)%3]: safe
        COMPUTE(&KsB[rd][0], &VsB[rd][0])
        rd = (rd == 2) ? 0 : rd + 1;
        wr = (wr == 2) ? 0 : wr + 1;
    }
    {   // peeled last tile
        asm volatile("s_waitcnt vmcnt(0)" ::: "memory");
        SB; __builtin_amdgcn_s_barrier(); SB;
        COMPUTE(&KsB[rd][0], &VsB[rd][0])
    }
    __syncthreads();   // full drain; reuse LDS as merge scratch

    // ---- epilogue: merge kh halves, store unnormalized o + row-sums ----
    float lr2 = lrP + __shfl_xor(lrP, 32);
    float* Om = reinterpret_cast<float*>(&KsB[0][0]);        // 32KB f32 [64][128]
    unsigned short* Oo = &VsB[0][0];                         // 16KB bf16 [64][128]

    if (kh == 1) {
        #pragma unroll
        for (int ob = 0; ob < 4; ++ob)
            #pragma unroll
            for (int r2 = 0; r2 < 16; ++r2) {
                int q = qsub * 32 + (r2 & 3) + 8 * (r2 >> 2) + 4 * h;
                Om[q * 128 + ob * 32 + l31] = o[ob][r2];
            }
        if (lane < 32) lrS[qsub * 32 + l31] = lr2;
    }
    __syncthreads();
    if (kh == 0) {
        #pragma unroll
        for (int ob = 0; ob < 4; ++ob)
            #pragma unroll
            for (int r2 = 0; r2 < 16; ++r2) {
                int q = qsub * 32 + (r2 & 3) + 8 * (r2 >> 2) + 4 * h;
                int idx = q * 128 + ob * 32 + l31;
                Oo[idx] = f2bf(o[ob][r2] + Om[idx]);
            }
        if (lane < 32)
            lrG[(size_t)b * NPOS + n0 + qsub * 32 + l31] = lr2 + lrS[qsub * 32 + l31];
    }
    __syncthreads();
    {
        const shortx8* src = reinterpret_cast<const shortx8*>(Oo);
        shortx8* dst = reinterpret_cast<shortx8*>(ao + ((size_t)b * NPOS + n0) * 128);
        #pragma unroll
        for (int i = 0; i < 4; ++i) dst[t + 256 * i] = src[t + 256 * i];
    }
    #undef STAGE
    #undef COMPUTE
    #undef SB
}

// ---------------------------------------------------------------------------
// K3: output projection + normalization + bias + residual, bf16 MFMA.
// y = x + bo + (wo . ao_unnorm) / lrow
// ---------------------------------------------------------------------------
__global__ __launch_bounds__(256) void out_proj(
    const float* __restrict__ x,
    const unsigned short* __restrict__ Wb,
    const float* __restrict__ bo,
    const unsigned short* __restrict__ ao,
    const float* __restrict__ lrG,
    float* __restrict__ y)
{
    const int b = blockIdx.y, n0 = blockIdx.x * 64;
    const int t = threadIdx.x, lane = t & 63, wave = t >> 6;
    const int l16 = lane & 15, lhi = lane >> 4;
    __shared__ __align__(16) unsigned short Wt[256 * 128];  // 64KB
    __shared__ __align__(16) unsigned short At[64 * 128];   // 16KB
    const unsigned short* wo = Wb + 98304;

    #pragma unroll
    for (int i = 0; i < 16; ++i) {   // wo tile [256][128]
        int c = (wave * 16 + i) * 64 + lane;
        int row = c >> 4, cin = (c & 15) ^ (row & 7);
        gll16(wo + (size_t)row * 128 + cin * 8, &Wt[0] + (wave * 16 + i) * 512);
    }
    #pragma unroll
    for (int i = 0; i < 4; ++i) {    // ao tile [64][128]
        int c = (wave * 4 + i) * 64 + lane;
        int row = c >> 4, cin = (c & 15) ^ (row & 7);
        gll16(ao + ((size_t)b * NPOS + n0 + row) * 128 + cin * 8, &At[0] + (wave * 4 + i) * 512);
    }
    __syncthreads();

    f32x4 acc[4][4];
    #pragma unroll
    for (int ab = 0; ab < 4; ++ab)
        #pragma unroll
        for (int nb = 0; nb < 4; ++nb) acc[ab][nb] = f32x4{0.f, 0.f, 0.f, 0.f};

    const int strip = wave * 64;
    #pragma unroll
    for (int ks = 0; ks < 4; ++ks) {
        shortx8 aW[4];
        #pragma unroll
        for (int ab = 0; ab < 4; ++ab) {
            int row = strip + ab * 16 + l16;
            int idx = (row * 128 + ks * 32 + lhi * 8) ^ ((row & 7) << 3);
            aW[ab] = *reinterpret_cast<const shortx8*>(Wt + idx);
        }
        #pragma unroll
        for (int nb = 0; nb < 4; ++nb) {
            int row = nb * 16 + l16;
            int idx = (row * 128 + ks * 32 + lhi * 8) ^ ((row & 7) << 3);
            shortx8 bA = *reinterpret_cast<const shortx8*>(At + idx);
            #pragma unroll
            for (int ab = 0; ab < 4; ++ab)
                acc[ab][nb] = __builtin_amdgcn_mfma_f32_16x16x32_bf16(aW[ab], bA, acc[ab][nb], 0, 0, 0);
        }
    }

    float inv[4];
    #pragma unroll
    for (int nb = 0; nb < 4; ++nb)
        inv[nb] = 1.0f / lrG[(size_t)b * NPOS + n0 + nb * 16 + l16];

    #pragma unroll
    for (int ab = 0; ab < 4; ++ab)
        #pragma unroll
        for (int j = 0; j < 4; ++j) {
            int oc = strip + ab * 16 + lhi * 4 + j;
            float bb = bo[oc];
            const float* xr = x + ((size_t)b * 256 + oc) * NPOS + n0;
            float* yr = y + ((size_t)b * 256 + oc) * NPOS + n0;
            #pragma unroll
            for (int nb = 0; nb < 4; ++nb) {
                int n = nb * 16 + l16;
                yr[n] = xr[n] + bb + acc[ab][nb][j] * inv[nb];
            }
        }
}

extern "C" void kernel_launch(void* const* d_in, const int* in_sizes, int n_in,
                              void* d_out, int out_size, void* d_ws, size_t ws_size,
                              hipStream_t stream)
{
    const float* x  = (const float*)d_in[0];
    const float* wq = (const float*)d_in[1];
    const float* bq = (const float*)d_in[2];
    const float* wk = (const float*)d_in[3];
    const float* bk = (const float*)d_in[4];
    const float* wv = (const float*)d_in[5];
    const float* bv = (const float*)d_in[6];
    const float* wo = (const float*)d_in[7];
    const float* bo = (const float*)d_in[8];
    float* y = (float*)d_out;

    const size_t sz = (size_t)NB * NPOS * 128;     // 3,211,264 elements
    unsigned short* qT = (unsigned short*)d_ws;    // sz
    unsigned short* kT = qT + sz;                  // sz
    unsigned short* vC = kT + sz;                  // sz
    unsigned short* ao = vC + sz;                  // sz
    unsigned short* Wb = ao + sz;                  // 131072
    float* lrG = (float*)(Wb + 131072);            // B*N f32 (100KB)
    // total ws use ~26 MB

    cast_w   <<<dim3(16, 4),     256, 0, stream>>>(wq, wk, wv, wo, Wb);
    qkv_fused<<<dim3(49, NB),    256, 0, stream>>>(x, Wb, bq, bk, bv, qT, kT, vC);
    attn_kernel<<<dim3(49, NB),  256, 0, stream>>>(qT, kT, vC, ao, lrG);
    out_proj <<<dim3(49, NB),    256, 0, stream>>>(x, Wb, bo, ao, lrG, y);
}

// Round 15
// 148.533 us; speedup vs baseline: 1.1608x; 1.1497x over previous
//
#include <hip/hip_runtime.h>
#include <hip/hip_bf16.h>
#include <math.h>

#define NPOS 3136   // 56*56
#define NB   8
#define LOG2E 1.44269504088896f
#define QSCALE (0.08838834764831845f * LOG2E)   // (1/sqrt(128)) * log2(e)
// softmax computed as p = 2^s directly (offset-invariant; |s| small)

typedef __attribute__((ext_vector_type(8))) short shortx8;    // 8 bf16
typedef __attribute__((ext_vector_type(4))) short shortx4;    // 4 bf16
typedef __attribute__((ext_vector_type(4))) float f32x4;
typedef __attribute__((ext_vector_type(16))) float f32x16;
typedef __attribute__((ext_vector_type(4))) unsigned int uint4v;

struct S8pair { shortx4 lo, hi; };

__device__ __forceinline__ float bf2f(unsigned short u) {
    unsigned int i = ((unsigned int)u) << 16;
    return __builtin_bit_cast(float, i);
}
__device__ __forceinline__ unsigned short f2bf(float f) {
    unsigned int i = __builtin_bit_cast(unsigned int, f);
    i += 0x7FFFu + ((i >> 16) & 1u);   // RNE
    return (unsigned short)(i >> 16);
}
// async global->LDS, 16B per lane; LDS dest = wave-uniform base + lane*16
__device__ __forceinline__ void gll16(const unsigned short* g, unsigned short* l) {
    __builtin_amdgcn_global_load_lds((const __attribute__((address_space(1))) void*)g,
                                     (__attribute__((address_space(3))) void*)l, 16, 0, 0);
}

// ---------------------------------------------------------------------------
// prep: weights -> bf16: Wb = [wq*QSCALE | wk | wv | wo], 32768 elements each
// ---------------------------------------------------------------------------
__global__ __launch_bounds__(256) void cast_w(
    const float* __restrict__ wq, const float* __restrict__ wk,
    const float* __restrict__ wv, const float* __restrict__ wo,
    unsigned short* __restrict__ Wb)
{
    const int sel = blockIdx.y;
    const float* src = (sel == 0) ? wq : (sel == 1) ? wk : (sel == 2) ? wv : wo;
    const float sc = (sel == 0) ? QSCALE : 1.0f;
    unsigned short* dst = Wb + sel * 32768;
    int i0 = (blockIdx.x * 256 + threadIdx.x) * 8;
    #pragma unroll
    for (int e = 0; e < 8; ++e) dst[i0 + e] = f2bf(src[i0 + e] * sc);
}

// ---------------------------------------------------------------------------
// K1: FUSED cast + QKV projection (r14, verified).  Builds Xt[64][256] bf16
// in LDS once; 3 sels x 2 k-halves of MFMA over it.
// ---------------------------------------------------------------------------
__global__ __launch_bounds__(256) void qkv_fused(
    const float* __restrict__ x,
    const unsigned short* __restrict__ Wb,
    const float* __restrict__ bq, const float* __restrict__ bk, const float* __restrict__ bv,
    unsigned short* __restrict__ qT, unsigned short* __restrict__ kT,
    unsigned short* __restrict__ vC)
{
    const int b = blockIdx.y, n0 = blockIdx.x * 64;
    const int t = threadIdx.x, lane = t & 63, wave = t >> 6;
    const int l16 = lane & 15, lhi = lane >> 4;
    __shared__ __align__(16) unsigned short Xt[64 * 256];   // 32KB
    __shared__ __align__(16) unsigned short Wt[128 * 128];  // 32KB
    __shared__ unsigned short Ls[64 * 66];                  // 8.25KB

    for (int cc = 0; cc < 4; ++cc) {
        {
            int r = t >> 2, q4 = t & 3;
            const float* src = x + ((size_t)b * 256 + cc * 64 + r) * NPOS + n0 + q4 * 16;
            #pragma unroll
            for (int i = 0; i < 16; ++i) Ls[r * 66 + q4 * 16 + i] = f2bf(src[i]);
        }
        __syncthreads();
        {
            int j = t >> 2, h4 = t & 3;
            shortx8 v0, v1;
            #pragma unroll
            for (int i = 0; i < 8; ++i) v0[i] = (short)Ls[(h4 * 16 + i) * 66 + j];
            #pragma unroll
            for (int i = 0; i < 8; ++i) v1[i] = (short)Ls[(h4 * 16 + 8 + i) * 66 + j];
            int X = (j & 7) << 3;
            int c0 = cc * 64 + h4 * 16;
            *reinterpret_cast<shortx8*>(&Xt[j * 256 + (c0 ^ X)]) = v0;
            *reinterpret_cast<shortx8*>(&Xt[j * 256 + ((c0 + 8) ^ X)]) = v1;
        }
        __syncthreads();
    }

    for (int sel = 0; sel < 3; ++sel) {
        const unsigned short* Wsel = Wb + sel * 32768;
        const float* bias = (sel == 0) ? bq : (sel == 1) ? bk : bv;

        f32x4 acc[2][4];
        #pragma unroll
        for (int ab = 0; ab < 2; ++ab)
            #pragma unroll
            for (int nb = 0; nb < 4; ++nb) acc[ab][nb] = f32x4{0.f, 0.f, 0.f, 0.f};

        for (int ks0 = 0; ks0 < 2; ++ks0) {
            const int k0 = ks0 * 128;
            __syncthreads();
            #pragma unroll
            for (int i = 0; i < 8; ++i) {   // W tile [128][128]
                int c = (wave * 8 + i) * 64 + lane;
                int row = c >> 4, cin = (c & 15) ^ (row & 7);
                gll16(Wsel + (size_t)row * 256 + k0 + cin * 8, &Wt[0] + (wave * 8 + i) * 512);
            }
            __syncthreads();
            #pragma unroll
            for (int ks = 0; ks < 4; ++ks) {
                shortx8 aW[2];
                #pragma unroll
                for (int ab = 0; ab < 2; ++ab) {
                    int row = wave * 32 + ab * 16 + l16;
                    int idx = (row * 128 + ks * 32 + lhi * 8) ^ ((row & 7) << 3);
                    aW[ab] = *reinterpret_cast<const shortx8*>(Wt + idx);
                }
                #pragma unroll
                for (int nb = 0; nb < 4; ++nb) {
                    int row = nb * 16 + l16;
                    int idx = row * 256 + ((k0 + ks * 32 + lhi * 8) ^ ((row & 7) << 3));
                    shortx8 bX = *reinterpret_cast<const shortx8*>(Xt + idx);
                    acc[0][nb] = __builtin_amdgcn_mfma_f32_16x16x32_bf16(aW[0], bX, acc[0][nb], 0, 0, 0);
                    acc[1][nb] = __builtin_amdgcn_mfma_f32_16x16x32_bf16(aW[1], bX, acc[1][nb], 0, 0, 0);
                }
            }
        }

        const int strip = wave * 32;
        if (sel < 2) {
            unsigned short* dst0 = ((sel == 0) ? qT : kT) + (size_t)b * NPOS * 128;
            const float bsc = (sel == 0) ? QSCALE : 1.0f;
            #pragma unroll
            for (int ab = 0; ab < 2; ++ab) {
                int ocb = strip + ab * 16 + lhi * 4;
                float bb[4];
                #pragma unroll
                for (int j = 0; j < 4; ++j) bb[j] = bias[ocb + j] * bsc;
                #pragma unroll
                for (int nb = 0; nb < 4; ++nb) {
                    int n = n0 + nb * 16 + l16;
                    shortx4 u;
                    #pragma unroll
                    for (int j = 0; j < 4; ++j) u[j] = (short)f2bf(acc[ab][nb][j] + bb[j]);
                    *reinterpret_cast<shortx4*>(dst0 + (size_t)n * 128 + ocb) = u;
                }
            }
        } else {
            #pragma unroll
            for (int ab = 0; ab < 2; ++ab)
                #pragma unroll
                for (int j = 0; j < 4; ++j) {
                    int oc = strip + ab * 16 + lhi * 4 + j;
                    float bb = bias[oc];
                    unsigned short* dst = vC + ((size_t)b * 128 + oc) * NPOS + n0;
                    #pragma unroll
                    for (int nb = 0; nb < 4; ++nb)
                        dst[nb * 16 + l16] = f2bf(acc[ab][nb][j] + bb);
                }
        }
    }
}

// ---------------------------------------------------------------------------
// K2: flash attention (r13 structure, VGPR cap REMOVED).
// PAIR-TILE: 128q/block, each wave 2 q-tiles sharing every K/V LDS read
// (halves LDS traffic per MFMA).  Z-SPLIT x2: grid 400, partial o/lr per
// key-half merged in out_proj.  r9 sync: 2-deep counted-vmcnt pipeline,
// raw barriers.  XCD-affine batch (id&7; 200 % 8 == 0).  LDS 64KB.
// VGPR ~204 (no launch_bounds cap -> no spill; 2 blocks/CU allowed).
// ---------------------------------------------------------------------------
__global__ __launch_bounds__(256) void attn_kernel(
    const unsigned short* __restrict__ qT,
    const unsigned short* __restrict__ kT,
    const unsigned short* __restrict__ vC,
    unsigned short* __restrict__ ao,     // [2][B*N*128]
    float* __restrict__ lrG)             // [2][B*N]
{
    const int id = blockIdx.x;
    const int z = id / 200;
    const int b = id & 7;                 // XCD-affine batch (200 % 8 == 0)
    const int ti = (id % 200) >> 3;       // 0..24
    const int lone = (ti == 24);
    const int n0 = ti * 128;
    const int kt0 = z ? 25 : 0, kt1 = z ? 49 : 25;
    const int t = threadIdx.x, lane = t & 63, wave = t >> 6;
    const int l31 = lane & 31, h = lane >> 5;
    const int qsub = wave >> 1, kh = wave & 1;

    __shared__ __align__(16) unsigned short KsB[2][64 * 128];   // 32KB
    __shared__ __align__(16) unsigned short VsB[2][128 * 64];   // 32KB

    // Q fragments: 2 q-tiles x 32 q-rows per wave
    shortx8 aQ[2][8];
    #pragma unroll
    for (int qt = 0; qt < 2; ++qt) {
        int qb = n0 + (lone ? 0 : qt * 64) + qsub * 32 + l31;
        const unsigned short* qp = qT + ((size_t)b * NPOS + qb) * 128 + h * 8;
        #pragma unroll
        for (int kk = 0; kk < 8; ++kk)
            aQ[qt][kk] = *reinterpret_cast<const shortx8*>(qp + kk * 16);
    }

    // staging sources (pre-swizzled so linear LDS dest == swizzled tile)
    const unsigned short* kSrc[4];
    const unsigned short* vSrc[4];
    unsigned sDst[4];
    #pragma unroll
    for (int i = 0; i < 4; ++i) {
        int c = (wave * 4 + i) * 64 + lane;
        int rK = c >> 4, cK = (c & 15) ^ (rK & 15);      // K tile [64][128]
        kSrc[i] = kT + ((size_t)b * NPOS + rK) * 128 + cK * 8;
        int rV = c >> 3, cV = (c & 7) ^ (rV & 7);        // V tile [128][64]
        vSrc[i] = vC + ((size_t)b * 128 + rV) * NPOS + cV * 8;
        sDst[i] = (wave * 4 + i) * 512;
    }

    // loop-invariant LDS read offsets
    unsigned kIdx[8];
    {
        int rowK = kh * 32 + l31;
        #pragma unroll
        for (int kk = 0; kk < 8; ++kk)
            kIdx[kk] = rowK * 128 + (((kk * 2 + h) ^ (rowK & 15)) * 8);
    }
    unsigned vIdx[4][2][2];
    #pragma unroll
    for (int ob = 0; ob < 4; ++ob) {
        int rowV = ob * 32 + l31;
        #pragma unroll
        for (int ks = 0; ks < 2; ++ks)
            #pragma unroll
            for (int rr = 0; rr < 2; ++rr)
                vIdx[ob][ks][rr] = rowV * 64 + h * 4
                    + (((kh * 4 + ks * 2 + rr) * 8) ^ ((rowV & 7) * 8));
    }

    f32x16 o[2][4];
    #pragma unroll
    for (int qt = 0; qt < 2; ++qt)
        #pragma unroll
        for (int ob = 0; ob < 4; ++ob)
            #pragma unroll
            for (int r2 = 0; r2 < 16; ++r2) o[qt][ob][r2] = 0.f;
    float lrP[2] = {0.f, 0.f};

    f32x16 FZ;
    #pragma unroll
    for (int r2 = 0; r2 < 16; ++r2) FZ[r2] = 0.f;
    asm volatile("" : "+v"(FZ));

    #define STAGE(kt_, buf_)                                                          \
        _Pragma("unroll")                                                             \
        for (int i = 0; i < 4; ++i) {                                                 \
            gll16(kSrc[i] + (size_t)(kt_) * 8192, &KsB[buf_][0] + sDst[i]);           \
            gll16(vSrc[i] + (kt_) * 64, &VsB[buf_][0] + sDst[i]);                     \
        }

    #define COMPUTE(Ks, Vs)                                                           \
    {                                                                                 \
        f32x16 s0_, s1_;                                                              \
        __builtin_amdgcn_s_setprio(1);                                                \
        {                                                                             \
            shortx8 kf0 = *reinterpret_cast<const shortx8*>((Ks) + kIdx[0]);          \
            s0_ = __builtin_amdgcn_mfma_f32_32x32x16_bf16(kf0, aQ[0][0], FZ, 0, 0, 0);\
            s1_ = __builtin_amdgcn_mfma_f32_32x32x16_bf16(kf0, aQ[1][0], FZ, 0, 0, 0);\
        }                                                                             \
        _Pragma("unroll")                                                             \
        for (int kk = 1; kk < 8; ++kk) {                                              \
            shortx8 kf = *reinterpret_cast<const shortx8*>((Ks) + kIdx[kk]);          \
            s0_ = __builtin_amdgcn_mfma_f32_32x32x16_bf16(kf, aQ[0][kk], s0_, 0, 0, 0); \
            s1_ = __builtin_amdgcn_mfma_f32_32x32x16_bf16(kf, aQ[1][kk], s1_, 0, 0, 0); \
        }                                                                             \
        __builtin_amdgcn_s_setprio(0);                                                \
        unsigned pk[2][8];                                                            \
        _Pragma("unroll")                                                             \
        for (int g = 0; g < 4; ++g) {                                                 \
            float a0 = exp2f(s0_[g * 4 + 0]), a1 = exp2f(s0_[g * 4 + 1]);             \
            float a2 = exp2f(s0_[g * 4 + 2]), a3 = exp2f(s0_[g * 4 + 3]);             \
            float c0 = exp2f(s1_[g * 4 + 0]), c1 = exp2f(s1_[g * 4 + 1]);             \
            float c2 = exp2f(s1_[g * 4 + 2]), c3 = exp2f(s1_[g * 4 + 3]);             \
            lrP[0] += (a0 + a1) + (a2 + a3);                                          \
            lrP[1] += (c0 + c1) + (c2 + c3);                                          \
            asm("v_cvt_pk_bf16_f32 %0, %1, %2" : "=v"(pk[0][g * 2 + 0]) : "v"(a0), "v"(a1)); \
            asm("v_cvt_pk_bf16_f32 %0, %1, %2" : "=v"(pk[0][g * 2 + 1]) : "v"(a2), "v"(a3)); \
            asm("v_cvt_pk_bf16_f32 %0, %1, %2" : "=v"(pk[1][g * 2 + 0]) : "v"(c0), "v"(c1)); \
            asm("v_cvt_pk_bf16_f32 %0, %1, %2" : "=v"(pk[1][g * 2 + 1]) : "v"(c2), "v"(c3)); \
        }                                                                             \
        __builtin_amdgcn_s_setprio(1);                                                \
        _Pragma("unroll")                                                             \
        for (int ks = 0; ks < 2; ++ks) {                                              \
            uint4v pv0 = {pk[0][ks * 4 + 0], pk[0][ks * 4 + 1], pk[0][ks * 4 + 2], pk[0][ks * 4 + 3]}; \
            uint4v pv1 = {pk[1][ks * 4 + 0], pk[1][ks * 4 + 1], pk[1][ks * 4 + 2], pk[1][ks * 4 + 3]}; \
            shortx8 PA0 = __builtin_bit_cast(shortx8, pv0);                           \
            shortx8 PA1 = __builtin_bit_cast(shortx8, pv1);                           \
            _Pragma("unroll")                                                         \
            for (int ob = 0; ob < 4; ++ob) {                                          \
                shortx4 lo = *reinterpret_cast<const shortx4*>((Vs) + vIdx[ob][ks][0]); \
                shortx4 hi = *reinterpret_cast<const shortx4*>((Vs) + vIdx[ob][ks][1]); \
                shortx8 bV = __builtin_bit_cast(shortx8, S8pair{lo, hi});             \
                o[0][ob] = __builtin_amdgcn_mfma_f32_32x32x16_bf16(PA0, bV, o[0][ob], 0, 0, 0); \
                o[1][ob] = __builtin_amdgcn_mfma_f32_32x32x16_bf16(PA1, bV, o[1][ob], 0, 0, 0); \
            }                                                                         \
        }                                                                             \
        __builtin_amdgcn_s_setprio(0);                                                \
    }

    #define SB __builtin_amdgcn_sched_barrier(0)

    // prologue: 2-deep prefetch (16 loads outstanding)
    STAGE(kt0, 0)
    STAGE(kt0 + 1, 1)

    int cur = 0;
    for (int kt = kt0; kt < kt1 - 1; ++kt) {
        asm volatile("s_waitcnt vmcnt(8)" ::: "memory");
        SB; __builtin_amdgcn_s_barrier(); SB;
        COMPUTE(&KsB[cur][0], &VsB[cur][0])
        SB; __builtin_amdgcn_s_barrier(); SB;
        if (kt < kt1 - 2) { STAGE(kt + 2, cur) }
        cur ^= 1;
    }
    {   // peeled last tile
        asm volatile("s_waitcnt vmcnt(0)" ::: "memory");
        SB; __builtin_amdgcn_s_barrier(); SB;
        COMPUTE(&KsB[cur][0], &VsB[cur][0])
    }
    __syncthreads();   // done with all LDS; reuse as merge scratch

    // ---- epilogue: per q-tile, merge kh halves, store partial o + lr ----
    float* Om = reinterpret_cast<float*>(&KsB[0][0]);        // 32KB f32 [64][128]
    float* lrS = reinterpret_cast<float*>(&VsB[1][0]);       // 256B
    unsigned short* Oo = &VsB[0][0];                         // 16KB bf16 [64][128]

    for (int qt = 0; qt < (lone ? 1 : 2); ++qt) {
        float lr2 = lrP[qt] + __shfl_xor(lrP[qt], 32);
        if (kh == 1) {
            #pragma unroll
            for (int ob = 0; ob < 4; ++ob)
                #pragma unroll
                for (int r2 = 0; r2 < 16; ++r2) {
                    int q = qsub * 32 + (r2 & 3) + 8 * (r2 >> 2) + 4 * h;
                    Om[q * 128 + ob * 32 + l31] = o[qt][ob][r2];
                }
            if (lane < 32) lrS[qsub * 32 + l31] = lr2;
        }
        __syncthreads();
        if (kh == 0) {
            #pragma unroll
            for (int ob = 0; ob < 4; ++ob)
                #pragma unroll
                for (int r2 = 0; r2 < 16; ++r2) {
                    int q = qsub * 32 + (r2 & 3) + 8 * (r2 >> 2) + 4 * h;
                    int idx = q * 128 + ob * 32 + l31;
                    Oo[idx] = f2bf(o[qt][ob][r2] + Om[idx]);
                }
            if (lane < 32)
                lrG[((size_t)z * NB + b) * NPOS + n0 + qt * 64 + qsub * 32 + l31]
                    = lr2 + lrS[qsub * 32 + l31];
        }
        __syncthreads();
        {
            const shortx8* src = reinterpret_cast<const shortx8*>(Oo);
            shortx8* dst = reinterpret_cast<shortx8*>(
                ao + (((size_t)z * NB + b) * NPOS + n0 + qt * 64) * 128);
            #pragma unroll
            for (int i = 0; i < 4; ++i) dst[t + 256 * i] = src[t + 256 * i];
        }
        __syncthreads();
    }
    #undef STAGE
    #undef COMPUTE
    #undef SB
}

// ---------------------------------------------------------------------------
// K3: output projection + z-merge + normalization + bias + residual.
// y = x + bo + (wo . (ao0 + ao1)) / (lr0 + lr1)   (dual f32 MFMA accumulate)
// ---------------------------------------------------------------------------
__global__ __launch_bounds__(256) void out_proj(
    const float* __restrict__ x,
    const unsigned short* __restrict__ Wb,
    const float* __restrict__ bo,
    const unsigned short* __restrict__ ao,   // [2][B*N*128]
    const float* __restrict__ lrG,           // [2][B*N]
    float* __restrict__ y)
{
    const int b = blockIdx.y, n0 = blockIdx.x * 64;
    const int t = threadIdx.x, lane = t & 63, wave = t >> 6;
    const int l16 = lane & 15, lhi = lane >> 4;
    __shared__ __align__(16) unsigned short Wt[256 * 128];     // 64KB
    __shared__ __align__(16) unsigned short At[2][64 * 128];   // 32KB
    const unsigned short* wo = Wb + 98304;

    #pragma unroll
    for (int i = 0; i < 16; ++i) {   // wo tile [256][128]
        int c = (wave * 16 + i) * 64 + lane;
        int row = c >> 4, cin = (c & 15) ^ (row & 7);
        gll16(wo + (size_t)row * 128 + cin * 8, &Wt[0] + (wave * 16 + i) * 512);
    }
    #pragma unroll
    for (int zz = 0; zz < 2; ++zz)
        #pragma unroll
        for (int i = 0; i < 4; ++i) {    // ao tiles [64][128] x2
            int c = (wave * 4 + i) * 64 + lane;
            int row = c >> 4, cin = (c & 15) ^ (row & 7);
            gll16(ao + (((size_t)zz * NB + b) * NPOS + n0 + row) * 128 + cin * 8,
                  &At[zz][0] + (wave * 4 + i) * 512);
        }
    __syncthreads();

    f32x4 acc[4][4];
    #pragma unroll
    for (int ab = 0; ab < 4; ++ab)
        #pragma unroll
        for (int nb = 0; nb < 4; ++nb) acc[ab][nb] = f32x4{0.f, 0.f, 0.f, 0.f};

    const int strip = wave * 64;
    #pragma unroll
    for (int ks = 0; ks < 4; ++ks) {
        shortx8 aW[4];
        #pragma unroll
        for (int ab = 0; ab < 4; ++ab) {
            int row = strip + ab * 16 + l16;
            int idx = (row * 128 + ks * 32 + lhi * 8) ^ ((row & 7) << 3);
            aW[ab] = *reinterpret_cast<const shortx8*>(Wt + idx);
        }
        #pragma unroll
        for (int nb = 0; nb < 4; ++nb) {
            int row = nb * 16 + l16;
            int idx = (row * 128 + ks * 32 + lhi * 8) ^ ((row & 7) << 3);
            shortx8 bA0 = *reinterpret_cast<const shortx8*>(&At[0][0] + idx);
            shortx8 bA1 = *reinterpret_cast<const shortx8*>(&At[1][0] + idx);
            #pragma unroll
            for (int ab = 0; ab < 4; ++ab) {
                acc[ab][nb] = __builtin_amdgcn_mfma_f32_16x16x32_bf16(aW[ab], bA0, acc[ab][nb], 0, 0, 0);
                acc[ab][nb] = __builtin_amdgcn_mfma_f32_16x16x32_bf16(aW[ab], bA1, acc[ab][nb], 0, 0, 0);
            }
        }
    }

    float inv[4];
    #pragma unroll
    for (int nb = 0; nb < 4; ++nb) {
        size_t n = (size_t)b * NPOS + n0 + nb * 16 + l16;
        inv[nb] = 1.0f / (lrG[n] + lrG[(size_t)NB * NPOS + n]);
    }

    #pragma unroll
    for (int ab = 0; ab < 4; ++ab)
        #pragma unroll
        for (int j = 0; j < 4; ++j) {
            int oc = strip + ab * 16 + lhi * 4 + j;
            float bb = bo[oc];
            const float* xr = x + ((size_t)b * 256 + oc) * NPOS + n0;
            float* yr = y + ((size_t)b * 256 + oc) * NPOS + n0;
            #pragma unroll
            for (int nb = 0; nb < 4; ++nb) {
                int n = nb * 16 + l16;
                yr[n] = xr[n] + bb + acc[ab][nb][j] * inv[nb];
            }
        }
}

extern "C" void kernel_launch(void* const* d_in, const int* in_sizes, int n_in,
                              void* d_out, int out_size, void* d_ws, size_t ws_size,
                              hipStream_t stream)
{
    const float* x  = (const float*)d_in[0];
    const float* wq = (const float*)d_in[1];
    const float* bq = (const float*)d_in[2];
    const float* wk = (const float*)d_in[3];
    const float* bk = (const float*)d_in[4];
    const float* wv = (const float*)d_in[5];
    const float* bv = (const float*)d_in[6];
    const float* wo = (const float*)d_in[7];
    const float* bo = (const float*)d_in[8];
    float* y = (float*)d_out;

    const size_t sz = (size_t)NB * NPOS * 128;     // 3,211,264 elements
    unsigned short* qT = (unsigned short*)d_ws;    // sz
    unsigned short* kT = qT + sz;                  // sz
    unsigned short* vC = kT + sz;                  // sz
    unsigned short* ao = vC + sz;                  // [2][sz]
    unsigned short* Wb = ao + 2 * sz;              // 131072
    float* lrG = (float*)(Wb + 131072);            // [2][B*N] f32 (200KB)
    // total ws use ~32.6 MB

    cast_w   <<<dim3(16, 4),    256, 0, stream>>>(wq, wk, wv, wo, Wb);
    qkv_fused<<<dim3(49, NB),   256, 0, stream>>>(x, Wb, bq, bk, bv, qT, kT, vC);
    attn_kernel<<<dim3(400),    256, 0, stream>>>(qT, kT, vC, ao, lrG);
    out_proj <<<dim3(49, NB),   256, 0, stream>>>(x, Wb, bo, ao, lrG, y);
}

// Round 16
// 113.267 us; speedup vs baseline: 1.5222x; 1.3114x over previous
//
#include <hip/hip_runtime.h>
#include <hip/hip_bf16.h>
#include <math.h>

#define NPOS 3136   // 56*56
#define NB   8
#define LOG2E 1.44269504088896f
#define QSCALE (0.08838834764831845f * LOG2E)   // (1/sqrt(128)) * log2(e)
// softmax computed as p = 2^s directly (offset-invariant; |s| small)

typedef __attribute__((ext_vector_type(8))) short shortx8;    // 8 bf16
typedef __attribute__((ext_vector_type(4))) short shortx4;    // 4 bf16
typedef __attribute__((ext_vector_type(4))) float f32x4;
typedef __attribute__((ext_vector_type(16))) float f32x16;
typedef __attribute__((ext_vector_type(4))) unsigned int uint4v;

struct S8pair { shortx4 lo, hi; };

__device__ __forceinline__ float bf2f(unsigned short u) {
    unsigned int i = ((unsigned int)u) << 16;
    return __builtin_bit_cast(float, i);
}
__device__ __forceinline__ unsigned short f2bf(float f) {
    unsigned int i = __builtin_bit_cast(unsigned int, f);
    i += 0x7FFFu + ((i >> 16) & 1u);   // RNE
    return (unsigned short)(i >> 16);
}
// async global->LDS, 16B per lane; LDS dest = wave-uniform base + lane*16
__device__ __forceinline__ void gll16(const unsigned short* g, unsigned short* l) {
    __builtin_amdgcn_global_load_lds((const __attribute__((address_space(1))) void*)g,
                                     (__attribute__((address_space(3))) void*)l, 16, 0, 0);
}

// ---------------------------------------------------------------------------
// prep: weights -> bf16: Wb = [wq*QSCALE | wk | wv | wo], 32768 elements each
// ---------------------------------------------------------------------------
__global__ __launch_bounds__(256) void cast_w(
    const float* __restrict__ wq, const float* __restrict__ wk,
    const float* __restrict__ wv, const float* __restrict__ wo,
    unsigned short* __restrict__ Wb)
{
    const int sel = blockIdx.y;
    const float* src = (sel == 0) ? wq : (sel == 1) ? wk : (sel == 2) ? wv : wo;
    const float sc = (sel == 0) ? QSCALE : 1.0f;
    unsigned short* dst = Wb + sel * 32768;
    int i0 = (blockIdx.x * 256 + threadIdx.x) * 8;
    #pragma unroll
    for (int e = 0; e < 8; ++e) dst[i0 + e] = f2bf(src[i0 + e] * sc);
}

// ---------------------------------------------------------------------------
// K1: FUSED cast + QKV projection (verified r14/r15).  Builds Xt[64][256]
// bf16 (transposed, XOR-swizzled) in LDS once; 3 sels x 2 k-halves of MFMA.
// Outputs qT,kT (B,N,128) (q pre-scaled, bias included); vC (B,128,N).
// ---------------------------------------------------------------------------
__global__ __launch_bounds__(256) void qkv_fused(
    const float* __restrict__ x,
    const unsigned short* __restrict__ Wb,
    const float* __restrict__ bq, const float* __restrict__ bk, const float* __restrict__ bv,
    unsigned short* __restrict__ qT, unsigned short* __restrict__ kT,
    unsigned short* __restrict__ vC)
{
    const int b = blockIdx.y, n0 = blockIdx.x * 64;
    const int t = threadIdx.x, lane = t & 63, wave = t >> 6;
    const int l16 = lane & 15, lhi = lane >> 4;
    __shared__ __align__(16) unsigned short Xt[64 * 256];   // 32KB
    __shared__ __align__(16) unsigned short Wt[128 * 128];  // 32KB
    __shared__ unsigned short Ls[64 * 66];                  // 8.25KB

    for (int cc = 0; cc < 4; ++cc) {
        {
            int r = t >> 2, q4 = t & 3;
            const float* src = x + ((size_t)b * 256 + cc * 64 + r) * NPOS + n0 + q4 * 16;
            #pragma unroll
            for (int i = 0; i < 16; ++i) Ls[r * 66 + q4 * 16 + i] = f2bf(src[i]);
        }
        __syncthreads();
        {
            int j = t >> 2, h4 = t & 3;
            shortx8 v0, v1;
            #pragma unroll
            for (int i = 0; i < 8; ++i) v0[i] = (short)Ls[(h4 * 16 + i) * 66 + j];
            #pragma unroll
            for (int i = 0; i < 8; ++i) v1[i] = (short)Ls[(h4 * 16 + 8 + i) * 66 + j];
            int X = (j & 7) << 3;
            int c0 = cc * 64 + h4 * 16;
            *reinterpret_cast<shortx8*>(&Xt[j * 256 + (c0 ^ X)]) = v0;
            *reinterpret_cast<shortx8*>(&Xt[j * 256 + ((c0 + 8) ^ X)]) = v1;
        }
        __syncthreads();
    }

    for (int sel = 0; sel < 3; ++sel) {
        const unsigned short* Wsel = Wb + sel * 32768;
        const float* bias = (sel == 0) ? bq : (sel == 1) ? bk : bv;

        f32x4 acc[2][4];
        #pragma unroll
        for (int ab = 0; ab < 2; ++ab)
            #pragma unroll
            for (int nb = 0; nb < 4; ++nb) acc[ab][nb] = f32x4{0.f, 0.f, 0.f, 0.f};

        for (int ks0 = 0; ks0 < 2; ++ks0) {
            const int k0 = ks0 * 128;
            __syncthreads();
            #pragma unroll
            for (int i = 0; i < 8; ++i) {   // W tile [128][128]
                int c = (wave * 8 + i) * 64 + lane;
                int row = c >> 4, cin = (c & 15) ^ (row & 7);
                gll16(Wsel + (size_t)row * 256 + k0 + cin * 8, &Wt[0] + (wave * 8 + i) * 512);
            }
            __syncthreads();
            #pragma unroll
            for (int ks = 0; ks < 4; ++ks) {
                shortx8 aW[2];
                #pragma unroll
                for (int ab = 0; ab < 2; ++ab) {
                    int row = wave * 32 + ab * 16 + l16;
                    int idx = (row * 128 + ks * 32 + lhi * 8) ^ ((row & 7) << 3);
                    aW[ab] = *reinterpret_cast<const shortx8*>(Wt + idx);
                }
                #pragma unroll
                for (int nb = 0; nb < 4; ++nb) {
                    int row = nb * 16 + l16;
                    int idx = row * 256 + ((k0 + ks * 32 + lhi * 8) ^ ((row & 7) << 3));
                    shortx8 bX = *reinterpret_cast<const shortx8*>(Xt + idx);
                    acc[0][nb] = __builtin_amdgcn_mfma_f32_16x16x32_bf16(aW[0], bX, acc[0][nb], 0, 0, 0);
                    acc[1][nb] = __builtin_amdgcn_mfma_f32_16x16x32_bf16(aW[1], bX, acc[1][nb], 0, 0, 0);
                }
            }
        }

        const int strip = wave * 32;
        if (sel < 2) {
            unsigned short* dst0 = ((sel == 0) ? qT : kT) + (size_t)b * NPOS * 128;
            const float bsc = (sel == 0) ? QSCALE : 1.0f;
            #pragma unroll
            for (int ab = 0; ab < 2; ++ab) {
                int ocb = strip + ab * 16 + lhi * 4;
                float bb[4];
                #pragma unroll
                for (int j = 0; j < 4; ++j) bb[j] = bias[ocb + j] * bsc;
                #pragma unroll
                for (int nb = 0; nb < 4; ++nb) {
                    int n = n0 + nb * 16 + l16;
                    shortx4 u;
                    #pragma unroll
                    for (int j = 0; j < 4; ++j) u[j] = (short)f2bf(acc[ab][nb][j] + bb[j]);
                    *reinterpret_cast<shortx4*>(dst0 + (size_t)n * 128 + ocb) = u;
                }
            }
        } else {
            #pragma unroll
            for (int ab = 0; ab < 2; ++ab)
                #pragma unroll
                for (int j = 0; j < 4; ++j) {
                    int oc = strip + ab * 16 + lhi * 4 + j;
                    float bb = bias[oc];
                    unsigned short* dst = vC + ((size_t)b * 128 + oc) * NPOS + n0;
                    #pragma unroll
                    for (int nb = 0; nb < 4; ++nb)
                        dst[nb * 16 + l16] = f2bf(acc[ab][nb][j] + bb);
                }
        }
    }
}

// ---------------------------------------------------------------------------
// K2: flash attention (r11 champion, verbatim).  32x32x16 MFMA, in-register
// P, 2-deep counted-vmcnt pipeline with raw barriers (no drains in loop),
// batch-per-XCD swizzle (id&7), persistent-zero C, p = 2^s, single QK chain.
// ---------------------------------------------------------------------------
__global__ __launch_bounds__(256) void attn_kernel(
    const unsigned short* __restrict__ qT,
    const unsigned short* __restrict__ kT,
    const unsigned short* __restrict__ vC,
    unsigned short* __restrict__ ao,
    float* __restrict__ lrG)
{
    const int i_lin = blockIdx.y * 49 + blockIdx.x;
    const int b = i_lin & 7;                 // XCD-affine batch
    const int n0 = (i_lin >> 3) * 64;        // query tile
    const int t = threadIdx.x, lane = t & 63, wave = t >> 6;
    const int l31 = lane & 31, h = lane >> 5;
    const int qsub = wave >> 1, kh = wave & 1;
    const int NT = NPOS / 64;                // 49

    __shared__ __align__(16) unsigned short KsB[2][64 * 128];   // 32KB
    __shared__ __align__(16) unsigned short VsB[2][128 * 64];   // 32KB
    __shared__ float lrS[64];

    shortx8 aQ[8];
    {
        const unsigned short* qp = qT + ((size_t)b * NPOS + n0 + qsub * 32 + l31) * 128 + h * 8;
        #pragma unroll
        for (int kk = 0; kk < 8; ++kk)
            aQ[kk] = *reinterpret_cast<const shortx8*>(qp + kk * 16);
    }

    const unsigned short* kSrc[4];
    const unsigned short* vSrc[4];
    unsigned sDst[4];
    #pragma unroll
    for (int i = 0; i < 4; ++i) {
        int c = (wave * 4 + i) * 64 + lane;
        int rK = c >> 4, cK = (c & 15) ^ (rK & 15);      // K tile [64][128]
        kSrc[i] = kT + ((size_t)b * NPOS + rK) * 128 + cK * 8;
        int rV = c >> 3, cV = (c & 7) ^ (rV & 7);        // V tile [128][64]
        vSrc[i] = vC + ((size_t)b * 128 + rV) * NPOS + cV * 8;
        sDst[i] = (wave * 4 + i) * 512;
    }

    unsigned kIdx[8];
    {
        int rowK = kh * 32 + l31;
        #pragma unroll
        for (int kk = 0; kk < 8; ++kk)
            kIdx[kk] = rowK * 128 + (((kk * 2 + h) ^ (rowK & 15)) * 8);
    }
    unsigned vIdx[4][2][2];
    #pragma unroll
    for (int ob = 0; ob < 4; ++ob) {
        int rowV = ob * 32 + l31;
        #pragma unroll
        for (int ks = 0; ks < 2; ++ks)
            #pragma unroll
            for (int rr = 0; rr < 2; ++rr)
                vIdx[ob][ks][rr] = rowV * 64 + h * 4
                    + (((kh * 4 + ks * 2 + rr) * 8) ^ ((rowV & 7) * 8));
    }

    f32x16 o[4];
    #pragma unroll
    for (int ob = 0; ob < 4; ++ob)
        #pragma unroll
        for (int r2 = 0; r2 < 16; ++r2) o[ob][r2] = 0.f;
    float lrP = 0.f;

    f32x16 FZ;
    #pragma unroll
    for (int r2 = 0; r2 < 16; ++r2) FZ[r2] = 0.f;
    asm volatile("" : "+v"(FZ));   // keep materialized in VGPRs

    #define STAGE(kt_, buf_)                                                          \
        _Pragma("unroll")                                                             \
        for (int i = 0; i < 4; ++i) {                                                 \
            gll16(kSrc[i] + (size_t)(kt_) * 8192, &KsB[buf_][0] + sDst[i]);           \
            gll16(vSrc[i] + (kt_) * 64, &VsB[buf_][0] + sDst[i]);                     \
        }

    #define COMPUTE(Ks, Vs)                                                           \
    {                                                                                 \
        f32x16 s_;                                                                    \
        __builtin_amdgcn_s_setprio(1);                                                \
        {                                                                             \
            shortx8 k0 = *reinterpret_cast<const shortx8*>((Ks) + kIdx[0]);           \
            s_ = __builtin_amdgcn_mfma_f32_32x32x16_bf16(k0, aQ[0], FZ, 0, 0, 0);     \
        }                                                                             \
        _Pragma("unroll")                                                             \
        for (int kk = 1; kk < 8; ++kk) {                                              \
            shortx8 kf = *reinterpret_cast<const shortx8*>((Ks) + kIdx[kk]);          \
            s_ = __builtin_amdgcn_mfma_f32_32x32x16_bf16(kf, aQ[kk], s_, 0, 0, 0);    \
        }                                                                             \
        __builtin_amdgcn_s_setprio(0);                                                \
        unsigned pk[8];                                                               \
        _Pragma("unroll")                                                             \
        for (int g = 0; g < 4; ++g) {                                                 \
            float p0 = exp2f(s_[g * 4 + 0]);                                          \
            float p1 = exp2f(s_[g * 4 + 1]);                                          \
            float p2 = exp2f(s_[g * 4 + 2]);                                          \
            float p3 = exp2f(s_[g * 4 + 3]);                                          \
            lrP += (p0 + p1) + (p2 + p3);                                             \
            asm("v_cvt_pk_bf16_f32 %0, %1, %2" : "=v"(pk[g * 2 + 0]) : "v"(p0), "v"(p1)); \
            asm("v_cvt_pk_bf16_f32 %0, %1, %2" : "=v"(pk[g * 2 + 1]) : "v"(p2), "v"(p3)); \
        }                                                                             \
        __builtin_amdgcn_s_setprio(1);                                                \
        _Pragma("unroll")                                                             \
        for (int ks = 0; ks < 2; ++ks) {                                              \
            uint4v pv = {pk[ks * 4 + 0], pk[ks * 4 + 1], pk[ks * 4 + 2], pk[ks * 4 + 3]}; \
            shortx8 PA = __builtin_bit_cast(shortx8, pv);                             \
            _Pragma("unroll")                                                         \
            for (int ob = 0; ob < 4; ++ob) {                                          \
                shortx4 lo = *reinterpret_cast<const shortx4*>((Vs) + vIdx[ob][ks][0]); \
                shortx4 hi = *reinterpret_cast<const shortx4*>((Vs) + vIdx[ob][ks][1]); \
                shortx8 bV = __builtin_bit_cast(shortx8, S8pair{lo, hi});             \
                o[ob] = __builtin_amdgcn_mfma_f32_32x32x16_bf16(PA, bV, o[ob], 0, 0, 0); \
            }                                                                         \
        }                                                                             \
        __builtin_amdgcn_s_setprio(0);                                                \
    }

    #define SB __builtin_amdgcn_sched_barrier(0)

    // prologue: 2-deep prefetch (16 loads outstanding)
    STAGE(0, 0)
    STAGE(1, 1)

    int cur = 0;
    for (int kt = 0; kt < NT - 1; ++kt) {
        asm volatile("s_waitcnt vmcnt(8)" ::: "memory");
        SB; __builtin_amdgcn_s_barrier(); SB;
        COMPUTE(&KsB[cur][0], &VsB[cur][0])
        SB; __builtin_amdgcn_s_barrier(); SB;
        if (kt < NT - 2) { STAGE(kt + 2, cur) }
        cur ^= 1;
    }
    {   // peeled last tile
        asm volatile("s_waitcnt vmcnt(0)" ::: "memory");
        SB; __builtin_amdgcn_s_barrier(); SB;
        COMPUTE(&KsB[cur][0], &VsB[cur][0])
    }
    __syncthreads();   // full drain; reuse LDS as merge scratch

    // ---- epilogue: merge kh halves, store unnormalized o + row-sums ----
    float lr2 = lrP + __shfl_xor(lrP, 32);
    float* Om = reinterpret_cast<float*>(&KsB[0][0]);        // 32KB f32 [64][128]
    unsigned short* Oo = &VsB[0][0];                         // 16KB bf16 [64][128]

    if (kh == 1) {
        #pragma unroll
        for (int ob = 0; ob < 4; ++ob)
            #pragma unroll
            for (int r2 = 0; r2 < 16; ++r2) {
                int q = qsub * 32 + (r2 & 3) + 8 * (r2 >> 2) + 4 * h;
                Om[q * 128 + ob * 32 + l31] = o[ob][r2];
            }
        if (lane < 32) lrS[qsub * 32 + l31] = lr2;
    }
    __syncthreads();
    if (kh == 0) {
        #pragma unroll
        for (int ob = 0; ob < 4; ++ob)
            #pragma unroll
            for (int r2 = 0; r2 < 16; ++r2) {
                int q = qsub * 32 + (r2 & 3) + 8 * (r2 >> 2) + 4 * h;
                int idx = q * 128 + ob * 32 + l31;
                Oo[idx] = f2bf(o[ob][r2] + Om[idx]);
            }
        if (lane < 32)
            lrG[(size_t)b * NPOS + n0 + qsub * 32 + l31] = lr2 + lrS[qsub * 32 + l31];
    }
    __syncthreads();
    {
        const shortx8* src = reinterpret_cast<const shortx8*>(Oo);
        shortx8* dst = reinterpret_cast<shortx8*>(ao + ((size_t)b * NPOS + n0) * 128);
        #pragma unroll
        for (int i = 0; i < 4; ++i) dst[t + 256 * i] = src[t + 256 * i];
    }
    #undef STAGE
    #undef COMPUTE
    #undef SB
}

// ---------------------------------------------------------------------------
// K3: output projection + normalization + bias + residual (r11 verbatim).
// y = x + bo + (wo . ao_unnorm) / lrow
// ---------------------------------------------------------------------------
__global__ __launch_bounds__(256) void out_proj(
    const float* __restrict__ x,
    const unsigned short* __restrict__ Wb,
    const float* __restrict__ bo,
    const unsigned short* __restrict__ ao,
    const float* __restrict__ lrG,
    float* __restrict__ y)
{
    const int b = blockIdx.y, n0 = blockIdx.x * 64;
    const int t = threadIdx.x, lane = t & 63, wave = t >> 6;
    const int l16 = lane & 15, lhi = lane >> 4;
    __shared__ __align__(16) unsigned short Wt[256 * 128];  // 64KB
    __shared__ __align__(16) unsigned short At[64 * 128];   // 16KB
    const unsigned short* wo = Wb + 98304;

    #pragma unroll
    for (int i = 0; i < 16; ++i) {   // wo tile [256][128]
        int c = (wave * 16 + i) * 64 + lane;
        int row = c >> 4, cin = (c & 15) ^ (row & 7);
        gll16(wo + (size_t)row * 128 + cin * 8, &Wt[0] + (wave * 16 + i) * 512);
    }
    #pragma unroll
    for (int i = 0; i < 4; ++i) {    // ao tile [64][128]
        int c = (wave * 4 + i) * 64 + lane;
        int row = c >> 4, cin = (c & 15) ^ (row & 7);
        gll16(ao + ((size_t)b * NPOS + n0 + row) * 128 + cin * 8, &At[0] + (wave * 4 + i) * 512);
    }
    __syncthreads();

    f32x4 acc[4][4];
    #pragma unroll
    for (int ab = 0; ab < 4; ++ab)
        #pragma unroll
        for (int nb = 0; nb < 4; ++nb) acc[ab][nb] = f32x4{0.f, 0.f, 0.f, 0.f};

    const int strip = wave * 64;
    #pragma unroll
    for (int ks = 0; ks < 4; ++ks) {
        shortx8 aW[4];
        #pragma unroll
        for (int ab = 0; ab < 4; ++ab) {
            int row = strip + ab * 16 + l16;
            int idx = (row * 128 + ks * 32 + lhi * 8) ^ ((row & 7) << 3);
            aW[ab] = *reinterpret_cast<const shortx8*>(Wt + idx);
        }
        #pragma unroll
        for (int nb = 0; nb < 4; ++nb) {
            int row = nb * 16 + l16;
            int idx = (row * 128 + ks * 32 + lhi * 8) ^ ((row & 7) << 3);
            shortx8 bA = *reinterpret_cast<const shortx8*>(At + idx);
            #pragma unroll
            for (int ab = 0; ab < 4; ++ab)
                acc[ab][nb] = __builtin_amdgcn_mfma_f32_16x16x32_bf16(aW[ab], bA, acc[ab][nb], 0, 0, 0);
        }
    }

    float inv[4];
    #pragma unroll
    for (int nb = 0; nb < 4; ++nb)
        inv[nb] = 1.0f / lrG[(size_t)b * NPOS + n0 + nb * 16 + l16];

    #pragma unroll
    for (int ab = 0; ab < 4; ++ab)
        #pragma unroll
        for (int j = 0; j < 4; ++j) {
            int oc = strip + ab * 16 + lhi * 4 + j;
            float bb = bo[oc];
            const float* xr = x + ((size_t)b * 256 + oc) * NPOS + n0;
            float* yr = y + ((size_t)b * 256 + oc) * NPOS + n0;
            #pragma unroll
            for (int nb = 0; nb < 4; ++nb) {
                int n = nb * 16 + l16;
                yr[n] = xr[n] + bb + acc[ab][nb][j] * inv[nb];
            }
        }
}

extern "C" void kernel_launch(void* const* d_in, const int* in_sizes, int n_in,
                              void* d_out, int out_size, void* d_ws, size_t ws_size,
                              hipStream_t stream)
{
    const float* x  = (const float*)d_in[0];
    const float* wq = (const float*)d_in[1];
    const float* bq = (const float*)d_in[2];
    const float* wk = (const float*)d_in[3];
    const float* bk = (const float*)d_in[4];
    const float* wv = (const float*)d_in[5];
    const float* bv = (const float*)d_in[6];
    const float* wo = (const float*)d_in[7];
    const float* bo = (const float*)d_in[8];
    float* y = (float*)d_out;

    const size_t sz = (size_t)NB * NPOS * 128;     // 3,211,264 elements
    unsigned short* qT = (unsigned short*)d_ws;    // sz
    unsigned short* kT = qT + sz;                  // sz
    unsigned short* vC = kT + sz;                  // sz
    unsigned short* ao = vC + sz;                  // sz
    unsigned short* Wb = ao + sz;                  // 131072
    float* lrG = (float*)(Wb + 131072);            // B*N f32 (100KB)
    // total ws use ~26 MB

    cast_w   <<<dim3(16, 4),    256, 0, stream>>>(wq, wk, wv, wo, Wb);
    qkv_fused<<<dim3(49, NB),   256, 0, stream>>>(x, Wb, bq, bk, bv, qT, kT, vC);
    attn_kernel<<<dim3(49, NB), 256, 0, stream>>>(qT, kT, vC, ao, lrG);
    out_proj <<<dim3(49, NB),   256, 0, stream>>>(x, Wb, bo, ao, lrG, y);
}